// Round 1
// baseline (389.344 us; speedup 1.0000x reference)
//
#include <hip/hip_runtime.h>

// Bahdanau attention, fused single-pass over encoder_outputs.
//   hidden:(32,1024) f32  enc:(32,2048,1024) f32  W:(2048,1) f32  b:(1,) f32
//   out: context (32,1024) f32
// softmax(hidden@W_h + enc@W_e + b) over s == softmax(enc@W_e) over s
// (per-batch additive constant cancels), so hidden/W_h/b are not needed.

#define H 1024
#define S 2048
#define B 32
#define CHUNKS 32                         // s-chunks per batch
#define ROWS_PER_BLOCK (S / CHUNKS)       // 64
#define ROWS_PER_WAVE (ROWS_PER_BLOCK/4)  // 16 (4 waves / 256-thread block)
#define PSTRIDE 1028                      // 1024 acc + 1 denom + pad (16B-aligned stride)

__global__ __launch_bounds__(256) void attn_pass1(
    const float* __restrict__ enc, const float* __restrict__ W,
    float* __restrict__ ws) {
  const int b     = blockIdx.x;
  const int chunk = blockIdx.y;
  const int tid   = threadIdx.x;
  const int wave  = tid >> 6;
  const int lane  = tid & 63;

  // W_e = W[H:2H]; each lane owns 16 of the 1024 weights (4x float4).
  const float4* We4 = (const float4*)(W + H);
  const float4 w0 = We4[lane];
  const float4 w1 = We4[lane + 64];
  const float4 w2 = We4[lane + 128];
  const float4 w3 = We4[lane + 192];

  float4 a0 = {0.f,0.f,0.f,0.f}, a1 = a0, a2 = a0, a3 = a0;
  float den = 0.f;

  const int s0 = chunk * ROWS_PER_BLOCK + wave * ROWS_PER_WAVE;
  const float4* base = (const float4*)(enc + ((size_t)b * S + s0) * H);

  for (int r = 0; r < ROWS_PER_WAVE; ++r) {
    const float4* row = base + (size_t)r * (H / 4);
    float4 e0 = row[lane];
    float4 e1 = row[lane + 64];
    float4 e2 = row[lane + 128];
    float4 e3 = row[lane + 192];

    // partial dot enc[s,:].W_e  (16 elems/lane)
    float p = e0.x*w0.x + e0.y*w0.y + e0.z*w0.z + e0.w*w0.w
            + e1.x*w1.x + e1.y*w1.y + e1.z*w1.z + e1.w*w1.w
            + e2.x*w2.x + e2.y*w2.y + e2.z*w2.z + e2.w*w2.w
            + e3.x*w3.x + e3.y*w3.y + e3.z*w3.z + e3.w*w3.w;
    // wave-wide allreduce (64 lanes)
    #pragma unroll
    for (int off = 32; off; off >>= 1) p += __shfl_xor(p, off, 64);

    // energies are O(1) here -> exp without max-subtraction is safe;
    // softmax is shift-invariant so this matches the reference.
    const float wt = __expf(p);

    a0.x += wt*e0.x; a0.y += wt*e0.y; a0.z += wt*e0.z; a0.w += wt*e0.w;
    a1.x += wt*e1.x; a1.y += wt*e1.y; a1.z += wt*e1.z; a1.w += wt*e1.w;
    a2.x += wt*e2.x; a2.y += wt*e2.y; a2.z += wt*e2.z; a2.w += wt*e2.w;
    a3.x += wt*e3.x; a3.y += wt*e3.y; a3.z += wt*e3.z; a3.w += wt*e3.w;
    den += wt;
  }

  // combine the 4 waves' partials in LDS, write one partial per block
  __shared__ float sm[4][H];
  __shared__ float smd[4];
  float4* smw = (float4*)sm[wave];
  smw[lane]       = a0;
  smw[lane + 64]  = a1;
  smw[lane + 128] = a2;
  smw[lane + 192] = a3;
  if (lane == 0) smd[wave] = den;
  __syncthreads();

  float4 v0 = ((float4*)sm[0])[tid];
  float4 v1 = ((float4*)sm[1])[tid];
  float4 v2 = ((float4*)sm[2])[tid];
  float4 v3 = ((float4*)sm[3])[tid];
  float4 sum;
  sum.x = v0.x + v1.x + v2.x + v3.x;
  sum.y = v0.y + v1.y + v2.y + v3.y;
  sum.z = v0.z + v1.z + v2.z + v3.z;
  sum.w = v0.w + v1.w + v2.w + v3.w;

  float* outp = ws + ((size_t)b * CHUNKS + chunk) * PSTRIDE;
  ((float4*)outp)[tid] = sum;
  if (tid == 0) outp[H] = smd[0] + smd[1] + smd[2] + smd[3];
}

__global__ __launch_bounds__(256) void attn_pass2(
    const float* __restrict__ ws, float* __restrict__ out) {
  const int b   = blockIdx.x;
  const int tid = threadIdx.x;
  const float* base = ws + (size_t)b * CHUNKS * PSTRIDE;

  float4 acc = {0.f,0.f,0.f,0.f};
  float den = 0.f;
  for (int p = 0; p < CHUNKS; ++p) {
    const float* pp = base + (size_t)p * PSTRIDE;
    float4 v = ((const float4*)pp)[tid];
    acc.x += v.x; acc.y += v.y; acc.z += v.z; acc.w += v.w;
    den += pp[H];
  }
  const float inv = 1.0f / den;
  float4 r;
  r.x = acc.x * inv; r.y = acc.y * inv; r.z = acc.z * inv; r.w = acc.w * inv;
  ((float4*)out)[b * (H / 4) + tid] = r;
}

extern "C" void kernel_launch(void* const* d_in, const int* in_sizes, int n_in,
                              void* d_out, int out_size, void* d_ws, size_t ws_size,
                              hipStream_t stream) {
  // d_in order: hidden(32*1024), encoder_outputs(32*2048*1024), W(2048), b(1)
  const float* enc = (const float*)d_in[1];
  const float* W   = (const float*)d_in[2];
  float* out = (float*)d_out;
  float* ws  = (float*)d_ws;   // needs 32*32*1028*4 = ~4.2 MB

  dim3 g1(B, CHUNKS);
  attn_pass1<<<g1, 256, 0, stream>>>(enc, W, ws);
  attn_pass2<<<B, 256, 0, stream>>>(ws, out);
}